// Round 7
// baseline (291.259 us; speedup 1.0000x reference)
//
#include <hip/hip_runtime.h>
#include <math.h>

#define EMB_D 128
#define BN_EPS 1e-5f
#define GATHER_BLOCKS 4096
#define OVF_CAP 8192

typedef float v2f __attribute__((ext_vector_type(2)));
typedef float v4f __attribute__((ext_vector_type(4)));

#if defined(__has_builtin)
#if __has_builtin(__builtin_amdgcn_cvt_pk_f32_fp8) && __has_builtin(__builtin_amdgcn_cvt_pk_fp8_f32)
#define FP8_HW 1
#endif
#endif

// ---------------- fp8 e4m3 helpers (HW cvt with SW fallback) ----------------
__device__ __forceinline__ unsigned int sw_f32_to_fp8(float x) {
    unsigned int u = __float_as_uint(x);
    unsigned int s = u >> 31;
    int e = (int)((u >> 23) & 0xff) - 127;
    unsigned int m = u & 0x7fffff;
    m += 0x7FFFF + ((m >> 20) & 1);
    if (m >> 23) { m = 0; e += 1; }
    int e8 = e + 7;
    if (e8 <= 0) return s << 7;
    if (e8 >= 15) return (s << 7) | 0x7E;
    return (s << 7) | ((unsigned)e8 << 3) | (m >> 20);
}

__device__ __forceinline__ float sw_fp8_to_f32(unsigned int v) {
    unsigned int s = (v >> 7) & 1, e = (v >> 3) & 15, m = v & 7;
    if (e == 0) return 0.0f;
    unsigned int bits = (s << 31) | ((e - 7 + 127) << 23) | (m << 20);
    return __uint_as_float(bits);
}

__device__ __forceinline__ unsigned int pack4_fp8(float4 v) {
#ifdef FP8_HW
    unsigned int o = 0;
    o = (unsigned int)__builtin_amdgcn_cvt_pk_fp8_f32(v.x, v.y, (int)o, false);
    o = (unsigned int)__builtin_amdgcn_cvt_pk_fp8_f32(v.z, v.w, (int)o, true);
    return o;
#else
    return sw_f32_to_fp8(v.x) | (sw_f32_to_fp8(v.y) << 8) |
           (sw_f32_to_fp8(v.z) << 16) | (sw_f32_to_fp8(v.w) << 24);
#endif
}

__device__ __forceinline__ float fp8x4_d2(unsigned int ua, unsigned int ub) {
#ifdef FP8_HW
    v2f a0 = __builtin_amdgcn_cvt_pk_f32_fp8((int)ua, false);
    v2f a1 = __builtin_amdgcn_cvt_pk_f32_fp8((int)ua, true);
    v2f b0 = __builtin_amdgcn_cvt_pk_f32_fp8((int)ub, false);
    v2f b1 = __builtin_amdgcn_cvt_pk_f32_fp8((int)ub, true);
    float dx = a0.x - b0.x, dy = a0.y - b0.y;
    float dz = a1.x - b1.x, dw = a1.y - b1.y;
#else
    float dx = sw_fp8_to_f32(ua & 0xff)         - sw_fp8_to_f32(ub & 0xff);
    float dy = sw_fp8_to_f32((ua >> 8) & 0xff)  - sw_fp8_to_f32((ub >> 8) & 0xff);
    float dz = sw_fp8_to_f32((ua >> 16) & 0xff) - sw_fp8_to_f32((ub >> 16) & 0xff);
    float dw = sw_fp8_to_f32(ua >> 24)          - sw_fp8_to_f32(ub >> 24);
#endif
    return fmaf(dx, dx, fmaf(dy, dy, fmaf(dz, dz, dw * dw)));
}

__device__ __forceinline__ float chunk_d2(uint4 a, uint4 b) {
    return fp8x4_d2(a.x, b.x) + fp8x4_d2(a.y, b.y)
         + fp8x4_d2(a.z, b.z) + fp8x4_d2(a.w, b.w);
}

// 2-lane-per-edge body (fallback kernels only)
__device__ __forceinline__ float edge_L(const unsigned char* src8,
                                        const unsigned char* dst8,
                                        int s, int d, int sub) {
    const uint4* sa = (const uint4*)(src8 + (long long)s * 128) + sub * 4;
    const uint4* sb = (const uint4*)(dst8 + (long long)d * 128) + sub * 4;
    const uint4 a0 = sa[0], a1 = sa[1], a2 = sa[2], a3 = sa[3];
    const uint4 b0 = sb[0], b1 = sb[1], b2 = sb[2], b3 = sb[3];
    float p = chunk_d2(a0, b0) + chunk_d2(a1, b1)
            + chunk_d2(a2, b2) + chunk_d2(a3, b3);
    p += __shfl_xor(p, 1, 64);
    return -logf(fmaxf(p, 1e-12f));
}

// flat per-XCD index -> record offset within the XCD's 8 bucket regions
__device__ __forceinline__ unsigned int flat_to_rec(unsigned int f,
                                                    const unsigned int (&pre)[9],
                                                    unsigned int cap) {
    unsigned int j = 0, pj = 0;
    #pragma unroll
    for (int k = 1; k < 8; ++k) {
        const bool ge = (f >= pre[k]);
        j  = ge ? (unsigned int)k : j;
        pj = ge ? pre[k] : pj;
    }
    return j * cap + (f - pj);
}

// ---------------------------------------------------------------------------
// K0: prep_bin — (A) convert src/dst f32 -> fp8 tables in ws;
//                (B) bin edges into 64 (src_slice, dst_slice) buckets AND
//                    copy graph indices -> float out[0..2E).
// cursors[0..63] = per-bucket counts, cursors[64] = overflow count
// (zero-initialized by a memsetAsync before launch).
// rec[b*cap + pos] = s | d<<20 | eid<<40; overflow at rec[64*cap + ..].
// ---------------------------------------------------------------------------
__global__ void prep_bin_kernel(const float* __restrict__ src,
                                const float* __restrict__ dst,
                                unsigned int* __restrict__ src8,
                                unsigned int* __restrict__ dst8,
                                long long nElem,
                                const int* __restrict__ g,
                                long long E,
                                float* __restrict__ out_graph,
                                unsigned long long* __restrict__ rec,
                                unsigned int* __restrict__ cursors,
                                unsigned int cap,
                                float inv_slice)
{
    // ---- phase A: table conversion (grid-stride) ----
    {
        const long long nthreads = (long long)gridDim.x * blockDim.x;
        const long long tid0 = (long long)blockIdx.x * blockDim.x + threadIdx.x;
        const long long nvec = nElem / 4;
        for (long long i = tid0; i < nvec; i += nthreads)
            src8[i] = pack4_fp8(((const float4*)src)[i]);
        for (long long i = tid0; i < nvec; i += nthreads)
            dst8[i] = pack4_fp8(((const float4*)dst)[i]);
    }

    // ---- phase B: binning + graph copy ----
    __shared__ unsigned int hist[64];
    __shared__ unsigned int curs[64];

    const long long chunkSz = (long long)blockDim.x * 8;   // 2048 edges
    const long long nchunks = (E + chunkSz - 1) / chunkSz;

    for (long long c = blockIdx.x; c < nchunks; c += gridDim.x) {
        const long long base = c * chunkSz;
        if (threadIdx.x < 64) hist[threadIdx.x] = 0;
        __syncthreads();

        int bb[8];
        unsigned long long pk[8];
        #pragma unroll
        for (int k = 0; k < 8; ++k) {
            const long long e = base + (long long)k * blockDim.x + threadIdx.x;
            bb[k] = -1;
            if (e < E) {
                const unsigned int s = (unsigned int)g[e];
                const unsigned int d = (unsigned int)g[E + e];
                __builtin_nontemporal_store((float)s, &out_graph[e]);
                __builtin_nontemporal_store((float)d, &out_graph[E + e]);
                int bs = (int)((float)s * inv_slice); bs = bs > 7 ? 7 : bs;
                int bd = (int)((float)d * inv_slice); bd = bd > 7 ? 7 : bd;
                bb[k] = bs * 8 + bd;
                pk[k] = (unsigned long long)s | ((unsigned long long)d << 20)
                      | ((unsigned long long)e << 40);
                atomicAdd(&hist[bb[k]], 1u);
            }
        }
        __syncthreads();
        if (threadIdx.x < 64 && hist[threadIdx.x] > 0)
            curs[threadIdx.x] = atomicAdd(&cursors[threadIdx.x], hist[threadIdx.x]);
        __syncthreads();

        #pragma unroll
        for (int k = 0; k < 8; ++k) {
            if (bb[k] >= 0) {
                unsigned int off = atomicAdd(&curs[bb[k]], 1u);
                if (off < cap) {
                    rec[(unsigned int)bb[k] * cap + off] = pk[k];
                } else {
                    unsigned int oo = atomicAdd(&cursors[64], 1u);
                    if (oo < OVF_CAP) rec[64u * cap + oo] = pk[k];
                }
            }
        }
        __syncthreads();
    }
}

// ---------------------------------------------------------------------------
// K1: gather v3 — XCD-pinned flat record loop, 8 lanes/edge, UNROLL 4 edges
// per group (16 independent row loads in flight per wave), 4096 blocks for
// block refill. NT scattered L store.
// ---------------------------------------------------------------------------
__global__ void edge_l_binned3_kernel(const unsigned char* __restrict__ src8,
                                      const unsigned char* __restrict__ dst8,
                                      const unsigned long long* __restrict__ rec,
                                      const unsigned int* __restrict__ cursors,
                                      unsigned int cap,
                                      float* __restrict__ l_out,
                                      double* __restrict__ acc)
{
    const int tid = threadIdx.x;
    const int sub = tid & 7;                 // lane within 8-lane edge group
    const int grp = tid >> 3;                // 0..31 edge group within block
    const int xcd = blockIdx.x & 7;
    const unsigned int local = blockIdx.x >> 3;
    const unsigned int nloc  = gridDim.x >> 3;

    // per-XCD bucket sizes -> register prefix sum
    unsigned int pre[9];
    pre[0] = 0;
    #pragma unroll
    for (int j = 0; j < 8; ++j) {
        unsigned int c = cursors[xcd * 8 + j];
        if (c > cap) c = cap;
        pre[j + 1] = pre[j] + c;
    }
    const unsigned int M = pre[8];
    const unsigned long long recBase = (unsigned long long)(xcd * 8) * cap;

    double sumL = 0.0, sumL2 = 0.0;

    const unsigned int perBlock = 128;       // 32 groups x 4 unroll
    const unsigned int stride = nloc * perBlock;

    for (unsigned int f0 = local * perBlock; f0 < M; f0 += stride) {
        unsigned int ff[4];
        bool ok[4];
        unsigned long long v[4];
        #pragma unroll
        for (int k = 0; k < 4; ++k) {
            ff[k] = f0 + (unsigned int)grp + 32u * (unsigned int)k;
            ok[k] = ff[k] < M;
            v[k] = 0ull;
            if (ok[k]) v[k] = rec[recBase + flat_to_rec(ff[k], pre, cap)];
        }

        uint4 A[4], B[4];
        #pragma unroll
        for (int k = 0; k < 4; ++k) {
            const int s = (int)(v[k] & 0xFFFFFu);
            const int d = (int)((v[k] >> 20) & 0xFFFFFu);
            A[k] = ((const uint4*)(src8 + (long long)s * 128))[sub];
            B[k] = ((const uint4*)(dst8 + (long long)d * 128))[sub];
        }

        float p[4];
        #pragma unroll
        for (int k = 0; k < 4; ++k)
            p[k] = chunk_d2(A[k], B[k]);

        #pragma unroll
        for (int k = 0; k < 4; ++k) {
            p[k] += __shfl_xor(p[k], 1, 64);
            p[k] += __shfl_xor(p[k], 2, 64);
            p[k] += __shfl_xor(p[k], 4, 64);
        }

        if (sub == 0) {
            #pragma unroll
            for (int k = 0; k < 4; ++k) {
                if (ok[k]) {
                    const float L = -logf(fmaxf(p[k], 1e-12f));
                    __builtin_nontemporal_store(L, &l_out[(long long)(v[k] >> 40)]);
                    sumL  += (double)L;
                    sumL2 += (double)L * (double)L;
                }
            }
        }
    }

    // overflow list (normally empty), swept by all blocks
    {
        unsigned int ovfN = cursors[64];
        if (ovfN > OVF_CAP) ovfN = OVF_CAP;
        const unsigned long long obase = 64ull * cap;
        const unsigned int gstride = gridDim.x * 32u;
        for (unsigned int f = blockIdx.x * 32u + (unsigned int)grp;
             f < ovfN; f += gstride) {
            const unsigned long long v = rec[obase + f];
            const int s = (int)(v & 0xFFFFFu);
            const int d = (int)((v >> 20) & 0xFFFFFu);
            const uint4 Av = ((const uint4*)(src8 + (long long)s * 128))[sub];
            const uint4 Bv = ((const uint4*)(dst8 + (long long)d * 128))[sub];
            float p = chunk_d2(Av, Bv);
            p += __shfl_xor(p, 1, 64);
            p += __shfl_xor(p, 2, 64);
            p += __shfl_xor(p, 4, 64);
            if (sub == 0) {
                const float L = -logf(fmaxf(p, 1e-12f));
                __builtin_nontemporal_store(L, &l_out[(long long)(v >> 40)]);
                sumL  += (double)L;
                sumL2 += (double)L * (double)L;
            }
        }
    }

    __shared__ double sA[256];
    __shared__ double sB[256];
    sA[tid] = sumL;
    sB[tid] = sumL2;
    __syncthreads();
    for (int ofs = 128; ofs >= 1; ofs >>= 1) {
        if (tid < ofs) {
            sA[tid] += sA[tid + ofs];
            sB[tid] += sB[tid + ofs];
        }
        __syncthreads();
    }
    if (tid == 0) {
        atomicAdd(&acc[0], sA[0]);
        atomicAdd(&acc[1], sB[0]);
    }
}

// ---------------------------------------------------------------------------
// Fallback A: fp8 tables, edge-order gather (used if ws can't hold rec).
// ---------------------------------------------------------------------------
__global__ void prep_tables_kernel(const float* __restrict__ src,
                                   const float* __restrict__ dst,
                                   unsigned int* __restrict__ src8,
                                   unsigned int* __restrict__ dst8,
                                   long long nElem)
{
    const long long nthreads = (long long)gridDim.x * blockDim.x;
    const long long tid0 = (long long)blockIdx.x * blockDim.x + threadIdx.x;
    const long long nvec = nElem / 4;
    for (long long i = tid0; i < nvec; i += nthreads)
        src8[i] = pack4_fp8(((const float4*)src)[i]);
    for (long long i = tid0; i < nvec; i += nthreads)
        dst8[i] = pack4_fp8(((const float4*)dst)[i]);
}

__global__ void edge_l_fp8_kernel(const unsigned char* __restrict__ src8,
                                  const unsigned char* __restrict__ dst8,
                                  const int* __restrict__ g,
                                  long long E,
                                  float*  __restrict__ l_out,
                                  double* __restrict__ acc)
{
    const int sub = threadIdx.x & 1;
    const int eg  = threadIdx.x >> 1;
    const long long stride = (long long)gridDim.x * 128;

    double sumL = 0.0, sumL2 = 0.0;

    long long e = (long long)blockIdx.x * 128 + eg;
    int s = 0, d = 0;
    if (e < E) { s = g[e]; d = g[E + e]; }

    while (e < E) {
        const long long en = e + stride;
        int sn = 0, dn = 0;
        if (en < E) { sn = g[en]; dn = g[E + en]; }
        const float L = edge_L(src8, dst8, s, d, sub);
        if (sub == 0) {
            l_out[e] = L;
            sumL  += (double)L;
            sumL2 += (double)L * (double)L;
        }
        e = en; s = sn; d = dn;
    }

    __shared__ double sA[256];
    __shared__ double sB[256];
    sA[threadIdx.x] = sumL;
    sB[threadIdx.x] = sumL2;
    __syncthreads();
    for (int ofs = 128; ofs >= 1; ofs >>= 1) {
        if ((int)threadIdx.x < ofs) {
            sA[threadIdx.x] += sA[threadIdx.x + ofs];
            sB[threadIdx.x] += sB[threadIdx.x + ofs];
        }
        __syncthreads();
    }
    if (threadIdx.x == 0) {
        atomicAdd(&acc[0], sA[0]);
        atomicAdd(&acc[1], sB[0]);
    }
}

// ---------------------------------------------------------------------------
// Fallback B: f32 tables in place (no usable ws)
// ---------------------------------------------------------------------------
__global__ void edge_l_kernel(const float* __restrict__ src,
                              const float* __restrict__ dst,
                              const int*   __restrict__ g,
                              long long E,
                              float*  __restrict__ l_out,
                              double* __restrict__ acc)
{
    const int sub  = threadIdx.x & 7;
    const int egrp = threadIdx.x >> 3;
    const long long stride = (long long)gridDim.x * 32;

    double sumL = 0.0, sumL2 = 0.0;

    long long e = (long long)blockIdx.x * 32 + egrp;
    int s = 0, d = 0;
    if (e < E) { s = g[e]; d = g[E + e]; }

    while (e < E) {
        const long long en = e + stride;
        int sn = 0, dn = 0;
        if (en < E) { sn = g[en]; dn = g[E + en]; }

        const float4* sa = (const float4*)(src + (long long)s * EMB_D);
        const float4* sb = (const float4*)(dst + (long long)d * EMB_D);
        const float4 a0 = sa[sub];      const float4 b0 = sb[sub];
        const float4 a1 = sa[sub + 8];  const float4 b1 = sb[sub + 8];
        const float4 a2 = sa[sub + 16]; const float4 b2 = sb[sub + 16];
        const float4 a3 = sa[sub + 24]; const float4 b3 = sb[sub + 24];

        float dx, dy, dz, dw, p = 0.f;
        dx = a0.x-b0.x; dy = a0.y-b0.y; dz = a0.z-b0.z; dw = a0.w-b0.w;
        p += fmaf(dx,dx,fmaf(dy,dy,fmaf(dz,dz,dw*dw)));
        dx = a1.x-b1.x; dy = a1.y-b1.y; dz = a1.z-b1.z; dw = a1.w-b1.w;
        p += fmaf(dx,dx,fmaf(dy,dy,fmaf(dz,dz,dw*dw)));
        dx = a2.x-b2.x; dy = a2.y-b2.y; dz = a2.z-b2.z; dw = a2.w-b2.w;
        p += fmaf(dx,dx,fmaf(dy,dy,fmaf(dz,dz,dw*dw)));
        dx = a3.x-b3.x; dy = a3.y-b3.y; dz = a3.z-b3.z; dw = a3.w-b3.w;
        p += fmaf(dx,dx,fmaf(dy,dy,fmaf(dz,dz,dw*dw)));

        p += __shfl_xor(p, 1, 64);
        p += __shfl_xor(p, 2, 64);
        p += __shfl_xor(p, 4, 64);

        if (sub == 0) {
            const float L = -logf(fmaxf(p, 1e-12f));
            l_out[e] = L;
            sumL  += (double)L;
            sumL2 += (double)L * (double)L;
        }
        e = en; s = sn; d = dn;
    }

    __shared__ double sA[256];
    __shared__ double sB[256];
    sA[threadIdx.x] = sumL;
    sB[threadIdx.x] = sumL2;
    __syncthreads();
    for (int ofs = 128; ofs >= 1; ofs >>= 1) {
        if ((int)threadIdx.x < ofs) {
            sA[threadIdx.x] += sA[threadIdx.x + ofs];
            sB[threadIdx.x] += sB[threadIdx.x + ofs];
        }
        __syncthreads();
    }
    if (threadIdx.x == 0) {
        atomicAdd(&acc[0], sA[0]);
        atomicAdd(&acc[1], sB[0]);
    }
}

// ---------------------------------------------------------------------------
// K2: BN, float4-vectorized. logits in place; sum(sigmoid) -> acc[2].
//     (ew is NOT written here — norm recomputes sigmoid from logits.)
// ---------------------------------------------------------------------------
__global__ void bn_sig_kernel(float* __restrict__ logits,
                              const double* __restrict__ acc,
                              double* __restrict__ sig_acc,
                              const float* __restrict__ bn_w,
                              const float* __restrict__ bn_b,
                              long long E)
{
    const long long nthreads = (long long)gridDim.x * blockDim.x;
    const long long tid0 = (long long)blockIdx.x * blockDim.x + threadIdx.x;

    __shared__ float s_mu, s_inv, s_w, s_b;
    if (threadIdx.x == 0) {
        const double mu  = acc[0] / (double)E;
        const double var = acc[1] / (double)E - mu * mu;
        s_mu  = (float)mu;
        s_inv = (float)(1.0 / sqrt(var + (double)BN_EPS));
        s_w   = bn_w[0];
        s_b   = bn_b[0];
    }
    __syncthreads();
    const float mu = s_mu, inv = s_inv, w = s_w, b = s_b;

    double sig = 0.0;
    const long long nvec = E / 4;
    for (long long i = tid0; i < nvec; i += nthreads) {
        float4 L = ((const float4*)logits)[i];
        float4 z;
        z.x = w * (L.x - mu) * inv + b;
        z.y = w * (L.y - mu) * inv + b;
        z.z = w * (L.z - mu) * inv + b;
        z.w = w * (L.w - mu) * inv + b;
        ((float4*)logits)[i] = z;
        const float sx = 1.0f / (1.0f + expf(-z.x));
        const float sy = 1.0f / (1.0f + expf(-z.y));
        const float sz = 1.0f / (1.0f + expf(-z.z));
        const float sw2 = 1.0f / (1.0f + expf(-z.w));
        sig += (double)(sx + sy) + (double)(sz + sw2);
    }
    for (long long i = nvec * 4 + tid0; i < E; i += nthreads) {
        const float L = logits[i];
        const float z = w * (L - mu) * inv + b;
        logits[i] = z;
        sig += (double)(1.0f / (1.0f + expf(-z)));
    }

    __shared__ double sS[256];
    sS[threadIdx.x] = sig;
    __syncthreads();
    for (int ofs = 128; ofs >= 1; ofs >>= 1) {
        if ((int)threadIdx.x < ofs)
            sS[threadIdx.x] += sS[threadIdx.x + ofs];
        __syncthreads();
    }
    if (threadIdx.x == 0)
        atomicAdd(sig_acc, sS[0]);
}

// ---------------------------------------------------------------------------
// K3: ew = sigmoid(logits) * E/sum_sigmoid; optional graph copy (fallbacks).
// ---------------------------------------------------------------------------
__global__ void norm_kernel(const float* __restrict__ logits,
                            float* __restrict__ ew,
                            const double* __restrict__ sig_acc,
                            const int* __restrict__ g,
                            float* __restrict__ out_graph,
                            int do_graph,
                            long long E)
{
    const long long nthreads = (long long)gridDim.x * blockDim.x;
    const long long tid0 = (long long)blockIdx.x * blockDim.x + threadIdx.x;
    const float scale = (float)((double)E / sig_acc[0]);

    const long long nvec = E / 4;
    for (long long i = tid0; i < nvec; i += nthreads) {
        const float4 z = ((const float4*)logits)[i];
        v4f v;
        v.x = scale / (1.0f + expf(-z.x));
        v.y = scale / (1.0f + expf(-z.y));
        v.z = scale / (1.0f + expf(-z.z));
        v.w = scale / (1.0f + expf(-z.w));
        __builtin_nontemporal_store(v, (v4f*)ew + i);
    }
    for (long long i = nvec * 4 + tid0; i < E; i += nthreads)
        ew[i] = scale / (1.0f + expf(-logits[i]));

    if (do_graph) {
        const long long gvec = (2 * E) / 4;
        for (long long i = tid0; i < gvec; i += nthreads) {
            const int4 v = ((const int4*)g)[i];
            float4 f;
            f.x = (float)v.x; f.y = (float)v.y; f.z = (float)v.z; f.w = (float)v.w;
            ((float4*)out_graph)[i] = f;
        }
        for (long long i = gvec * 4 + tid0; i < 2 * E; i += nthreads)
            out_graph[i] = (float)g[i];
    }
}

extern "C" void kernel_launch(void* const* d_in, const int* in_sizes, int n_in,
                              void* d_out, int out_size, void* d_ws, size_t ws_size,
                              hipStream_t stream) {
    const float* src  = (const float*)d_in[0];
    const float* dst  = (const float*)d_in[1];
    const int*   g    = (const int*)d_in[2];
    const float* bn_w = (const float*)d_in[3];
    const float* bn_b = (const float*)d_in[4];

    const long long N = (long long)in_sizes[0] / EMB_D;
    const long long E = (long long)in_sizes[2] / 2;

    float* out        = (float*)d_out;
    float* out_graph  = out;            // [0, 2E)
    float* out_ew     = out + 2 * E;    // [2E, 3E)
    float* out_logits = out + 3 * E;    // [3E, 4E)  (holds L first)

    // ws layout: [0,24) acc doubles | [64,324) cursors u32[65] | 512: tables | rec
    double*       acc     = (double*)d_ws;
    unsigned int* cursors = (unsigned int*)((char*)d_ws + 64);
    unsigned char* src8   = (unsigned char*)d_ws + 512;
    unsigned char* dst8   = src8 + (size_t)N * EMB_D;
    unsigned long long* rec = (unsigned long long*)(dst8 + (size_t)N * EMB_D);

    const unsigned int cap = (unsigned int)(E / 64 + 2048);
    const size_t need_full = 512 + (size_t)N * EMB_D * 2
                           + ((size_t)64 * cap + OVF_CAP) * 8;
    const size_t need_fp8  = 512 + (size_t)N * EMB_D * 2;

    const int slice_sz = (int)((N + 7) / 8);
    const float inv_slice = 1.0f / (float)slice_sz;

    (void)hipMemsetAsync(d_ws, 0, 512, stream);   // zeroes acc + cursors

    if (ws_size >= need_full && N < (1 << 20) && E < (1LL << 24)) {
        prep_bin_kernel<<<4096, 256, 0, stream>>>(src, dst,
                                                  (unsigned int*)src8,
                                                  (unsigned int*)dst8,
                                                  N * EMB_D, g, E, out_graph,
                                                  rec, cursors, cap, inv_slice);
        edge_l_binned3_kernel<<<GATHER_BLOCKS, 256, 0, stream>>>(
            src8, dst8, rec, cursors, cap, out_logits, acc);
        bn_sig_kernel<<<1024, 256, 0, stream>>>(out_logits, acc, &acc[2],
                                                bn_w, bn_b, E);
        norm_kernel<<<1024, 256, 0, stream>>>(out_logits, out_ew, &acc[2],
                                              g, out_graph, 0, E);
    } else if (ws_size >= need_fp8) {
        prep_tables_kernel<<<4096, 256, 0, stream>>>(src, dst,
                                                     (unsigned int*)src8,
                                                     (unsigned int*)dst8,
                                                     N * EMB_D);
        edge_l_fp8_kernel<<<4096, 256, 0, stream>>>(src8, dst8, g, E,
                                                    out_logits, acc);
        bn_sig_kernel<<<1024, 256, 0, stream>>>(out_logits, acc, &acc[2],
                                                bn_w, bn_b, E);
        norm_kernel<<<1024, 256, 0, stream>>>(out_logits, out_ew, &acc[2],
                                              g, out_graph, 1, E);
    } else {
        edge_l_kernel<<<4096, 256, 0, stream>>>(src, dst, g, E, out_logits, acc);
        bn_sig_kernel<<<1024, 256, 0, stream>>>(out_logits, acc, &acc[2],
                                                bn_w, bn_b, E);
        norm_kernel<<<1024, 256, 0, stream>>>(out_logits, out_ew, &acc[2],
                                              g, out_graph, 1, E);
    }
}

// Round 8
// 262.101 us; speedup vs baseline: 1.1112x; 1.1112x over previous
//
#include <hip/hip_runtime.h>
#include <math.h>

#define EMB_D 128
#define BN_EPS 1e-5f
#define GATHER_BLOCKS 2048
#define OVF_CAP 8192

typedef float v2f __attribute__((ext_vector_type(2)));
typedef float v4f __attribute__((ext_vector_type(4)));

#if defined(__has_builtin)
#if __has_builtin(__builtin_amdgcn_cvt_pk_f32_fp8) && __has_builtin(__builtin_amdgcn_cvt_pk_fp8_f32)
#define FP8_HW 1
#endif
#endif

// ---------------- fp8 e4m3 helpers (HW cvt with SW fallback) ----------------
__device__ __forceinline__ unsigned int sw_f32_to_fp8(float x) {
    unsigned int u = __float_as_uint(x);
    unsigned int s = u >> 31;
    int e = (int)((u >> 23) & 0xff) - 127;
    unsigned int m = u & 0x7fffff;
    m += 0x7FFFF + ((m >> 20) & 1);
    if (m >> 23) { m = 0; e += 1; }
    int e8 = e + 7;
    if (e8 <= 0) return s << 7;
    if (e8 >= 15) return (s << 7) | 0x7E;
    return (s << 7) | ((unsigned)e8 << 3) | (m >> 20);
}

__device__ __forceinline__ float sw_fp8_to_f32(unsigned int v) {
    unsigned int s = (v >> 7) & 1, e = (v >> 3) & 15, m = v & 7;
    if (e == 0) return 0.0f;
    unsigned int bits = (s << 31) | ((e - 7 + 127) << 23) | (m << 20);
    return __uint_as_float(bits);
}

__device__ __forceinline__ unsigned int pack4_fp8(float4 v) {
#ifdef FP8_HW
    unsigned int o = 0;
    o = (unsigned int)__builtin_amdgcn_cvt_pk_fp8_f32(v.x, v.y, (int)o, false);
    o = (unsigned int)__builtin_amdgcn_cvt_pk_fp8_f32(v.z, v.w, (int)o, true);
    return o;
#else
    return sw_f32_to_fp8(v.x) | (sw_f32_to_fp8(v.y) << 8) |
           (sw_f32_to_fp8(v.z) << 16) | (sw_f32_to_fp8(v.w) << 24);
#endif
}

__device__ __forceinline__ float fp8x4_d2(unsigned int ua, unsigned int ub) {
#ifdef FP8_HW
    v2f a0 = __builtin_amdgcn_cvt_pk_f32_fp8((int)ua, false);
    v2f a1 = __builtin_amdgcn_cvt_pk_f32_fp8((int)ua, true);
    v2f b0 = __builtin_amdgcn_cvt_pk_f32_fp8((int)ub, false);
    v2f b1 = __builtin_amdgcn_cvt_pk_f32_fp8((int)ub, true);
    float dx = a0.x - b0.x, dy = a0.y - b0.y;
    float dz = a1.x - b1.x, dw = a1.y - b1.y;
#else
    float dx = sw_fp8_to_f32(ua & 0xff)         - sw_fp8_to_f32(ub & 0xff);
    float dy = sw_fp8_to_f32((ua >> 8) & 0xff)  - sw_fp8_to_f32((ub >> 8) & 0xff);
    float dz = sw_fp8_to_f32((ua >> 16) & 0xff) - sw_fp8_to_f32((ub >> 16) & 0xff);
    float dw = sw_fp8_to_f32(ua >> 24)          - sw_fp8_to_f32(ub >> 24);
#endif
    return fmaf(dx, dx, fmaf(dy, dy, fmaf(dz, dz, dw * dw)));
}

__device__ __forceinline__ float chunk_d2(uint4 a, uint4 b) {
    return fp8x4_d2(a.x, b.x) + fp8x4_d2(a.y, b.y)
         + fp8x4_d2(a.z, b.z) + fp8x4_d2(a.w, b.w);
}

// 2-lane-per-edge body (fallback kernels only)
__device__ __forceinline__ float edge_L(const unsigned char* src8,
                                        const unsigned char* dst8,
                                        int s, int d, int sub) {
    const uint4* sa = (const uint4*)(src8 + (long long)s * 128) + sub * 4;
    const uint4* sb = (const uint4*)(dst8 + (long long)d * 128) + sub * 4;
    const uint4 a0 = sa[0], a1 = sa[1], a2 = sa[2], a3 = sa[3];
    const uint4 b0 = sb[0], b1 = sb[1], b2 = sb[2], b3 = sb[3];
    float p = chunk_d2(a0, b0) + chunk_d2(a1, b1)
            + chunk_d2(a2, b2) + chunk_d2(a3, b3);
    p += __shfl_xor(p, 1, 64);
    return -logf(fmaxf(p, 1e-12f));
}

// flat per-XCD index -> record offset within the XCD's 8 bucket regions
__device__ __forceinline__ unsigned int flat_to_rec(unsigned int f,
                                                    const unsigned int (&pre)[9],
                                                    unsigned int cap) {
    unsigned int j = 0, pj = 0;
    #pragma unroll
    for (int k = 1; k < 8; ++k) {
        const bool ge = (f >= pre[k]);
        j  = ge ? (unsigned int)k : j;
        pj = ge ? pre[k] : pj;
    }
    return j * cap + (f - pj);
}

// ---------------------------------------------------------------------------
// K0: prep_bin — (A) convert src/dst f32 -> fp8 tables in ws + vectorized
//     graph copy -> float out[0..2E); (B) bin edges into 64 buckets.
// cursors[0..63] = per-bucket counts, cursors[64] = overflow count
// (zero-initialized by a memsetAsync before launch).
// rec[b*cap + pos] = s | d<<20 | eid<<40; overflow at rec[64*cap + ..].
// ---------------------------------------------------------------------------
__global__ void prep_bin_kernel(const float* __restrict__ src,
                                const float* __restrict__ dst,
                                unsigned int* __restrict__ src8,
                                unsigned int* __restrict__ dst8,
                                long long nElem,
                                const int* __restrict__ g,
                                long long E,
                                float* __restrict__ out_graph,
                                unsigned long long* __restrict__ rec,
                                unsigned int* __restrict__ cursors,
                                unsigned int cap,
                                float inv_slice)
{
    // ---- phase A: table conversion + graph copy (grid-stride, vectorized) --
    {
        const long long nthreads = (long long)gridDim.x * blockDim.x;
        const long long tid0 = (long long)blockIdx.x * blockDim.x + threadIdx.x;
        const long long nvec = nElem / 4;
        for (long long i = tid0; i < nvec; i += nthreads)
            src8[i] = pack4_fp8(((const float4*)src)[i]);
        for (long long i = tid0; i < nvec; i += nthreads)
            dst8[i] = pack4_fp8(((const float4*)dst)[i]);

        const long long gvec = (2 * E) / 4;
        for (long long i = tid0; i < gvec; i += nthreads) {
            const int4 v = ((const int4*)g)[i];
            v4f f;
            f.x = (float)v.x; f.y = (float)v.y; f.z = (float)v.z; f.w = (float)v.w;
            __builtin_nontemporal_store(f, (v4f*)out_graph + i);
        }
        for (long long i = gvec * 4 + tid0; i < 2 * E; i += nthreads)
            out_graph[i] = (float)g[i];
    }

    // ---- phase B: binning ----
    __shared__ unsigned int hist[64];
    __shared__ unsigned int curs[64];

    const long long chunkSz = (long long)blockDim.x * 8;   // 2048 edges
    const long long nchunks = (E + chunkSz - 1) / chunkSz;

    for (long long c = blockIdx.x; c < nchunks; c += gridDim.x) {
        const long long base = c * chunkSz;
        if (threadIdx.x < 64) hist[threadIdx.x] = 0;
        __syncthreads();

        int bb[8];
        unsigned long long pk[8];
        #pragma unroll
        for (int k = 0; k < 8; ++k) {
            const long long e = base + (long long)k * blockDim.x + threadIdx.x;
            bb[k] = -1;
            if (e < E) {
                const unsigned int s = (unsigned int)g[e];
                const unsigned int d = (unsigned int)g[E + e];
                int bs = (int)((float)s * inv_slice); bs = bs > 7 ? 7 : bs;
                int bd = (int)((float)d * inv_slice); bd = bd > 7 ? 7 : bd;
                bb[k] = bs * 8 + bd;
                pk[k] = (unsigned long long)s | ((unsigned long long)d << 20)
                      | ((unsigned long long)e << 40);
                atomicAdd(&hist[bb[k]], 1u);
            }
        }
        __syncthreads();
        if (threadIdx.x < 64 && hist[threadIdx.x] > 0)
            curs[threadIdx.x] = atomicAdd(&cursors[threadIdx.x], hist[threadIdx.x]);
        __syncthreads();

        #pragma unroll
        for (int k = 0; k < 8; ++k) {
            if (bb[k] >= 0) {
                unsigned int off = atomicAdd(&curs[bb[k]], 1u);
                if (off < cap) {
                    rec[(unsigned int)bb[k] * cap + off] = pk[k];
                } else {
                    unsigned int oo = atomicAdd(&cursors[64], 1u);
                    if (oo < OVF_CAP) rec[64u * cap + oo] = pk[k];
                }
            }
        }
        __syncthreads();
    }
}

// ---------------------------------------------------------------------------
// K1: gather (R5 winner) — XCD-pinned flat record loop, 8 lanes/edge,
// unroll 2 edges/group (compiler's VGPR sweet spot), 2048 blocks.
// NT scattered L store. Block-reduce sum(L), sum(L^2) -> acc.
// ---------------------------------------------------------------------------
__global__ void edge_l_binned2_kernel(const unsigned char* __restrict__ src8,
                                      const unsigned char* __restrict__ dst8,
                                      const unsigned long long* __restrict__ rec,
                                      const unsigned int* __restrict__ cursors,
                                      unsigned int cap,
                                      float* __restrict__ l_out,
                                      double* __restrict__ acc)
{
    const int tid = threadIdx.x;
    const int sub = tid & 7;                 // lane within 8-lane edge group
    const int grp = tid >> 3;                // 0..31 edge group within block
    const int xcd = blockIdx.x & 7;
    const unsigned int local = blockIdx.x >> 3;
    const unsigned int nloc  = gridDim.x >> 3;

    // per-XCD bucket sizes -> register prefix sum
    unsigned int pre[9];
    pre[0] = 0;
    #pragma unroll
    for (int j = 0; j < 8; ++j) {
        unsigned int c = cursors[xcd * 8 + j];
        if (c > cap) c = cap;
        pre[j + 1] = pre[j] + c;
    }
    const unsigned int M = pre[8];
    const unsigned long long recBase = (unsigned long long)(xcd * 8) * cap;

    double sumL = 0.0, sumL2 = 0.0;

    const unsigned int perBlock = 64;        // 32 groups x 2 unroll
    const unsigned int stride = nloc * perBlock;

    for (unsigned int f0 = local * perBlock; f0 < M; f0 += stride) {
        const unsigned int f1 = f0 + (unsigned int)grp;
        const unsigned int f2 = f1 + 32u;
        const bool ok1 = f1 < M;
        const bool ok2 = f2 < M;

        unsigned long long v1 = 0ull, v2 = 0ull;
        if (ok1) v1 = rec[recBase + flat_to_rec(f1, pre, cap)];
        if (ok2) v2 = rec[recBase + flat_to_rec(f2, pre, cap)];

        const int s1 = (int)(v1 & 0xFFFFFu);
        const int d1 = (int)((v1 >> 20) & 0xFFFFFu);
        const int s2 = (int)(v2 & 0xFFFFFu);
        const int d2i = (int)((v2 >> 20) & 0xFFFFFu);

        const uint4 A1 = ((const uint4*)(src8 + (long long)s1 * 128))[sub];
        const uint4 B1 = ((const uint4*)(dst8 + (long long)d1 * 128))[sub];
        const uint4 A2 = ((const uint4*)(src8 + (long long)s2 * 128))[sub];
        const uint4 B2 = ((const uint4*)(dst8 + (long long)d2i * 128))[sub];

        float p1 = chunk_d2(A1, B1);
        float p2 = chunk_d2(A2, B2);

        p1 += __shfl_xor(p1, 1, 64);
        p1 += __shfl_xor(p1, 2, 64);
        p1 += __shfl_xor(p1, 4, 64);
        p2 += __shfl_xor(p2, 1, 64);
        p2 += __shfl_xor(p2, 2, 64);
        p2 += __shfl_xor(p2, 4, 64);

        if (sub == 0) {
            if (ok1) {
                const float L = -logf(fmaxf(p1, 1e-12f));
                __builtin_nontemporal_store(L, &l_out[(long long)(v1 >> 40)]);
                sumL  += (double)L;
                sumL2 += (double)L * (double)L;
            }
            if (ok2) {
                const float L = -logf(fmaxf(p2, 1e-12f));
                __builtin_nontemporal_store(L, &l_out[(long long)(v2 >> 40)]);
                sumL  += (double)L;
                sumL2 += (double)L * (double)L;
            }
        }
    }

    // overflow list (normally empty), swept by all blocks
    {
        unsigned int ovfN = cursors[64];
        if (ovfN > OVF_CAP) ovfN = OVF_CAP;
        const unsigned long long obase = 64ull * cap;
        const unsigned int gstride = gridDim.x * 32u;
        for (unsigned int f = blockIdx.x * 32u + (unsigned int)grp;
             f < ovfN; f += gstride) {
            const unsigned long long v = rec[obase + f];
            const int s = (int)(v & 0xFFFFFu);
            const int d = (int)((v >> 20) & 0xFFFFFu);
            const uint4 Av = ((const uint4*)(src8 + (long long)s * 128))[sub];
            const uint4 Bv = ((const uint4*)(dst8 + (long long)d * 128))[sub];
            float p = chunk_d2(Av, Bv);
            p += __shfl_xor(p, 1, 64);
            p += __shfl_xor(p, 2, 64);
            p += __shfl_xor(p, 4, 64);
            if (sub == 0) {
                const float L = -logf(fmaxf(p, 1e-12f));
                __builtin_nontemporal_store(L, &l_out[(long long)(v >> 40)]);
                sumL  += (double)L;
                sumL2 += (double)L * (double)L;
            }
        }
    }

    __shared__ double sA[256];
    __shared__ double sB[256];
    sA[tid] = sumL;
    sB[tid] = sumL2;
    __syncthreads();
    for (int ofs = 128; ofs >= 1; ofs >>= 1) {
        if (tid < ofs) {
            sA[tid] += sA[tid + ofs];
            sB[tid] += sB[tid + ofs];
        }
        __syncthreads();
    }
    if (tid == 0) {
        atomicAdd(&acc[0], sA[0]);
        atomicAdd(&acc[1], sB[0]);
    }
}

// ---------------------------------------------------------------------------
// Fallback A: fp8 tables, edge-order gather (used if ws can't hold rec).
// ---------------------------------------------------------------------------
__global__ void prep_tables_kernel(const float* __restrict__ src,
                                   const float* __restrict__ dst,
                                   unsigned int* __restrict__ src8,
                                   unsigned int* __restrict__ dst8,
                                   long long nElem)
{
    const long long nthreads = (long long)gridDim.x * blockDim.x;
    const long long tid0 = (long long)blockIdx.x * blockDim.x + threadIdx.x;
    const long long nvec = nElem / 4;
    for (long long i = tid0; i < nvec; i += nthreads)
        src8[i] = pack4_fp8(((const float4*)src)[i]);
    for (long long i = tid0; i < nvec; i += nthreads)
        dst8[i] = pack4_fp8(((const float4*)dst)[i]);
}

__global__ void edge_l_fp8_kernel(const unsigned char* __restrict__ src8,
                                  const unsigned char* __restrict__ dst8,
                                  const int* __restrict__ g,
                                  long long E,
                                  float*  __restrict__ l_out,
                                  double* __restrict__ acc)
{
    const int sub = threadIdx.x & 1;
    const int eg  = threadIdx.x >> 1;
    const long long stride = (long long)gridDim.x * 128;

    double sumL = 0.0, sumL2 = 0.0;

    long long e = (long long)blockIdx.x * 128 + eg;
    int s = 0, d = 0;
    if (e < E) { s = g[e]; d = g[E + e]; }

    while (e < E) {
        const long long en = e + stride;
        int sn = 0, dn = 0;
        if (en < E) { sn = g[en]; dn = g[E + en]; }
        const float L = edge_L(src8, dst8, s, d, sub);
        if (sub == 0) {
            l_out[e] = L;
            sumL  += (double)L;
            sumL2 += (double)L * (double)L;
        }
        e = en; s = sn; d = dn;
    }

    __shared__ double sA[256];
    __shared__ double sB[256];
    sA[threadIdx.x] = sumL;
    sB[threadIdx.x] = sumL2;
    __syncthreads();
    for (int ofs = 128; ofs >= 1; ofs >>= 1) {
        if ((int)threadIdx.x < ofs) {
            sA[threadIdx.x] += sA[threadIdx.x + ofs];
            sB[threadIdx.x] += sB[threadIdx.x + ofs];
        }
        __syncthreads();
    }
    if (threadIdx.x == 0) {
        atomicAdd(&acc[0], sA[0]);
        atomicAdd(&acc[1], sB[0]);
    }
}

// ---------------------------------------------------------------------------
// Fallback B: f32 tables in place (no usable ws)
// ---------------------------------------------------------------------------
__global__ void edge_l_kernel(const float* __restrict__ src,
                              const float* __restrict__ dst,
                              const int*   __restrict__ g,
                              long long E,
                              float*  __restrict__ l_out,
                              double* __restrict__ acc)
{
    const int sub  = threadIdx.x & 7;
    const int egrp = threadIdx.x >> 3;
    const long long stride = (long long)gridDim.x * 32;

    double sumL = 0.0, sumL2 = 0.0;

    long long e = (long long)blockIdx.x * 32 + egrp;
    int s = 0, d = 0;
    if (e < E) { s = g[e]; d = g[E + e]; }

    while (e < E) {
        const long long en = e + stride;
        int sn = 0, dn = 0;
        if (en < E) { sn = g[en]; dn = g[E + en]; }

        const float4* sa = (const float4*)(src + (long long)s * EMB_D);
        const float4* sb = (const float4*)(dst + (long long)d * EMB_D);
        const float4 a0 = sa[sub];      const float4 b0 = sb[sub];
        const float4 a1 = sa[sub + 8];  const float4 b1 = sb[sub + 8];
        const float4 a2 = sa[sub + 16]; const float4 b2 = sb[sub + 16];
        const float4 a3 = sa[sub + 24]; const float4 b3 = sb[sub + 24];

        float dx, dy, dz, dw, p = 0.f;
        dx = a0.x-b0.x; dy = a0.y-b0.y; dz = a0.z-b0.z; dw = a0.w-b0.w;
        p += fmaf(dx,dx,fmaf(dy,dy,fmaf(dz,dz,dw*dw)));
        dx = a1.x-b1.x; dy = a1.y-b1.y; dz = a1.z-b1.z; dw = a1.w-b1.w;
        p += fmaf(dx,dx,fmaf(dy,dy,fmaf(dz,dz,dw*dw)));
        dx = a2.x-b2.x; dy = a2.y-b2.y; dz = a2.z-b2.z; dw = a2.w-b2.w;
        p += fmaf(dx,dx,fmaf(dy,dy,fmaf(dz,dz,dw*dw)));
        dx = a3.x-b3.x; dy = a3.y-b3.y; dz = a3.z-b3.z; dw = a3.w-b3.w;
        p += fmaf(dx,dx,fmaf(dy,dy,fmaf(dz,dz,dw*dw)));

        p += __shfl_xor(p, 1, 64);
        p += __shfl_xor(p, 2, 64);
        p += __shfl_xor(p, 4, 64);

        if (sub == 0) {
            const float L = -logf(fmaxf(p, 1e-12f));
            l_out[e] = L;
            sumL  += (double)L;
            sumL2 += (double)L * (double)L;
        }
        e = en; s = sn; d = dn;
    }

    __shared__ double sA[256];
    __shared__ double sB[256];
    sA[threadIdx.x] = sumL;
    sB[threadIdx.x] = sumL2;
    __syncthreads();
    for (int ofs = 128; ofs >= 1; ofs >>= 1) {
        if ((int)threadIdx.x < ofs) {
            sA[threadIdx.x] += sA[threadIdx.x + ofs];
            sB[threadIdx.x] += sB[threadIdx.x + ofs];
        }
        __syncthreads();
    }
    if (threadIdx.x == 0) {
        atomicAdd(&acc[0], sA[0]);
        atomicAdd(&acc[1], sB[0]);
    }
}

// ---------------------------------------------------------------------------
// K2: BN, float4-vectorized. logits in place; sum(sigmoid) -> acc[2].
//     (ew is NOT written here — norm recomputes sigmoid from logits.)
// ---------------------------------------------------------------------------
__global__ void bn_sig_kernel(float* __restrict__ logits,
                              const double* __restrict__ acc,
                              double* __restrict__ sig_acc,
                              const float* __restrict__ bn_w,
                              const float* __restrict__ bn_b,
                              long long E)
{
    const long long nthreads = (long long)gridDim.x * blockDim.x;
    const long long tid0 = (long long)blockIdx.x * blockDim.x + threadIdx.x;

    __shared__ float s_mu, s_inv, s_w, s_b;
    if (threadIdx.x == 0) {
        const double mu  = acc[0] / (double)E;
        const double var = acc[1] / (double)E - mu * mu;
        s_mu  = (float)mu;
        s_inv = (float)(1.0 / sqrt(var + (double)BN_EPS));
        s_w   = bn_w[0];
        s_b   = bn_b[0];
    }
    __syncthreads();
    const float mu = s_mu, inv = s_inv, w = s_w, b = s_b;

    double sig = 0.0;
    const long long nvec = E / 4;
    for (long long i = tid0; i < nvec; i += nthreads) {
        float4 L = ((const float4*)logits)[i];
        float4 z;
        z.x = w * (L.x - mu) * inv + b;
        z.y = w * (L.y - mu) * inv + b;
        z.z = w * (L.z - mu) * inv + b;
        z.w = w * (L.w - mu) * inv + b;
        ((float4*)logits)[i] = z;
        const float sx = 1.0f / (1.0f + expf(-z.x));
        const float sy = 1.0f / (1.0f + expf(-z.y));
        const float sz = 1.0f / (1.0f + expf(-z.z));
        const float sw2 = 1.0f / (1.0f + expf(-z.w));
        sig += (double)(sx + sy) + (double)(sz + sw2);
    }
    for (long long i = nvec * 4 + tid0; i < E; i += nthreads) {
        const float L = logits[i];
        const float z = w * (L - mu) * inv + b;
        logits[i] = z;
        sig += (double)(1.0f / (1.0f + expf(-z)));
    }

    __shared__ double sS[256];
    sS[threadIdx.x] = sig;
    __syncthreads();
    for (int ofs = 128; ofs >= 1; ofs >>= 1) {
        if ((int)threadIdx.x < ofs)
            sS[threadIdx.x] += sS[threadIdx.x + ofs];
        __syncthreads();
    }
    if (threadIdx.x == 0)
        atomicAdd(sig_acc, sS[0]);
}

// ---------------------------------------------------------------------------
// K3: ew = sigmoid(logits) * E/sum_sigmoid; optional graph copy (fallbacks).
// ---------------------------------------------------------------------------
__global__ void norm_kernel(const float* __restrict__ logits,
                            float* __restrict__ ew,
                            const double* __restrict__ sig_acc,
                            const int* __restrict__ g,
                            float* __restrict__ out_graph,
                            int do_graph,
                            long long E)
{
    const long long nthreads = (long long)gridDim.x * blockDim.x;
    const long long tid0 = (long long)blockIdx.x * blockDim.x + threadIdx.x;
    const float scale = (float)((double)E / sig_acc[0]);

    const long long nvec = E / 4;
    for (long long i = tid0; i < nvec; i += nthreads) {
        const float4 z = ((const float4*)logits)[i];
        v4f v;
        v.x = scale / (1.0f + expf(-z.x));
        v.y = scale / (1.0f + expf(-z.y));
        v.z = scale / (1.0f + expf(-z.z));
        v.w = scale / (1.0f + expf(-z.w));
        __builtin_nontemporal_store(v, (v4f*)ew + i);
    }
    for (long long i = nvec * 4 + tid0; i < E; i += nthreads)
        ew[i] = scale / (1.0f + expf(-logits[i]));

    if (do_graph) {
        const long long gvec = (2 * E) / 4;
        for (long long i = tid0; i < gvec; i += nthreads) {
            const int4 v = ((const int4*)g)[i];
            float4 f;
            f.x = (float)v.x; f.y = (float)v.y; f.z = (float)v.z; f.w = (float)v.w;
            ((float4*)out_graph)[i] = f;
        }
        for (long long i = gvec * 4 + tid0; i < 2 * E; i += nthreads)
            out_graph[i] = (float)g[i];
    }
}

extern "C" void kernel_launch(void* const* d_in, const int* in_sizes, int n_in,
                              void* d_out, int out_size, void* d_ws, size_t ws_size,
                              hipStream_t stream) {
    const float* src  = (const float*)d_in[0];
    const float* dst  = (const float*)d_in[1];
    const int*   g    = (const int*)d_in[2];
    const float* bn_w = (const float*)d_in[3];
    const float* bn_b = (const float*)d_in[4];

    const long long N = (long long)in_sizes[0] / EMB_D;
    const long long E = (long long)in_sizes[2] / 2;

    float* out        = (float*)d_out;
    float* out_graph  = out;            // [0, 2E)
    float* out_ew     = out + 2 * E;    // [2E, 3E)
    float* out_logits = out + 3 * E;    // [3E, 4E)  (holds L first)

    // ws layout: [0,24) acc doubles | [64,324) cursors u32[65] | 512: tables | rec
    double*       acc     = (double*)d_ws;
    unsigned int* cursors = (unsigned int*)((char*)d_ws + 64);
    unsigned char* src8   = (unsigned char*)d_ws + 512;
    unsigned char* dst8   = src8 + (size_t)N * EMB_D;
    unsigned long long* rec = (unsigned long long*)(dst8 + (size_t)N * EMB_D);

    const unsigned int cap = (unsigned int)(E / 64 + 2048);
    const size_t need_full = 512 + (size_t)N * EMB_D * 2
                           + ((size_t)64 * cap + OVF_CAP) * 8;
    const size_t need_fp8  = 512 + (size_t)N * EMB_D * 2;

    const int slice_sz = (int)((N + 7) / 8);
    const float inv_slice = 1.0f / (float)slice_sz;

    (void)hipMemsetAsync(d_ws, 0, 512, stream);   // zeroes acc + cursors

    if (ws_size >= need_full && N < (1 << 20) && E < (1LL << 24)) {
        prep_bin_kernel<<<4096, 256, 0, stream>>>(src, dst,
                                                  (unsigned int*)src8,
                                                  (unsigned int*)dst8,
                                                  N * EMB_D, g, E, out_graph,
                                                  rec, cursors, cap, inv_slice);
        edge_l_binned2_kernel<<<GATHER_BLOCKS, 256, 0, stream>>>(
            src8, dst8, rec, cursors, cap, out_logits, acc);
        bn_sig_kernel<<<1024, 256, 0, stream>>>(out_logits, acc, &acc[2],
                                                bn_w, bn_b, E);
        norm_kernel<<<1024, 256, 0, stream>>>(out_logits, out_ew, &acc[2],
                                              g, out_graph, 0, E);
    } else if (ws_size >= need_fp8) {
        prep_tables_kernel<<<4096, 256, 0, stream>>>(src, dst,
                                                     (unsigned int*)src8,
                                                     (unsigned int*)dst8,
                                                     N * EMB_D);
        edge_l_fp8_kernel<<<4096, 256, 0, stream>>>(src8, dst8, g, E,
                                                    out_logits, acc);
        bn_sig_kernel<<<1024, 256, 0, stream>>>(out_logits, acc, &acc[2],
                                                bn_w, bn_b, E);
        norm_kernel<<<1024, 256, 0, stream>>>(out_logits, out_ew, &acc[2],
                                              g, out_graph, 1, E);
    } else {
        edge_l_kernel<<<4096, 256, 0, stream>>>(src, dst, g, E, out_logits, acc);
        bn_sig_kernel<<<1024, 256, 0, stream>>>(out_logits, acc, &acc[2],
                                                bn_w, bn_b, E);
        norm_kernel<<<1024, 256, 0, stream>>>(out_logits, out_ew, &acc[2],
                                              g, out_graph, 1, E);
    }
}